// Round 1
// baseline (128.155 us; speedup 1.0000x reference)
//
#include <hip/hip_runtime.h>

// Weighted squared-error reduction:
// result = sum_{b,s,c,h,w} visweight[b,s,h,w] * (conv - out)^2 / 1024
// Shapes: output/convdata [8,300,4,32,32] f32, visweight [8,300,32,32] f32.
// Memory-bound: ~88.5 MB read -> ~14 us floor at 6.3 TB/s.

__global__ __launch_bounds__(256) void loss_reduce_kernel(
    const float4* __restrict__ outp,
    const float4* __restrict__ conv,
    const float4* __restrict__ wgt,
    float* __restrict__ result,
    int n4)  // total float4 count over [B,S,C,H,W] = 2,457,600
{
    float acc = 0.0f;
    const int stride = gridDim.x * blockDim.x;
    for (int i = blockIdx.x * blockDim.x + threadIdx.x; i < n4; i += stride) {
        // per (b,s): 4 channels x 1024 elems = 1024 float4; per channel: 256 float4
        const int hw4 = i & 255;          // float4 index within the 32x32 plane
        const int bs  = i >> 10;          // (b,s) slab index
        const float4 o = outp[i];
        const float4 c = conv[i];
        const float4 w = wgt[bs * 256 + hw4];
        const float dx = c.x - o.x;
        const float dy = c.y - o.y;
        const float dz = c.z - o.z;
        const float dw = c.w - o.w;
        acc += w.x * dx * dx + w.y * dy * dy + w.z * dz * dz + w.w * dw * dw;
    }

    // 64-lane wave reduction
    #pragma unroll
    for (int off = 32; off > 0; off >>= 1)
        acc += __shfl_down(acc, off, 64);

    __shared__ float sbuf[4];
    const int lane = threadIdx.x & 63;
    const int wid  = threadIdx.x >> 6;
    if (lane == 0) sbuf[wid] = acc;
    __syncthreads();
    if (threadIdx.x == 0) {
        float t = (sbuf[0] + sbuf[1]) + (sbuf[2] + sbuf[3]);
        atomicAdd(result, t * (1.0f / 1024.0f));
    }
}

extern "C" void kernel_launch(void* const* d_in, const int* in_sizes, int n_in,
                              void* d_out, int out_size, void* d_ws, size_t ws_size,
                              hipStream_t stream) {
    const float4* outp = (const float4*)d_in[0];  // output   [8,300,4,32,32]
    const float4* conv = (const float4*)d_in[1];  // convdata [8,300,4,32,32]
    const float4* wgt  = (const float4*)d_in[2];  // visweight[8,300,32,32]
    float* result = (float*)d_out;

    const int n4 = in_sizes[0] / 4;  // 2,457,600

    // d_out is poisoned to 0xAA before every launch; zero it (async, capture-safe).
    hipMemsetAsync(d_out, 0, sizeof(float) * out_size, stream);

    const int block = 256;
    const int grid  = 2048;  // grid-stride; ~4.7 float4 per thread
    loss_reduce_kernel<<<grid, block, 0, stream>>>(outp, conv, wgt, result, n4);
}

// Round 2
// 105.681 us; speedup vs baseline: 1.2127x; 1.2127x over previous
//
#include <hip/hip_runtime.h>

// result = sum_{b,s,c,h,w} visweight[b,s,h,w] * (conv - out)^2 / 1024
// output/convdata [8,300,4,32,32] f32 (9,830,400 elems = 2,457,600 float4)
// visweight [8,300,32,32] f32.
//
// Exact tiling: 2,457,600 float4 = 1200 blocks x 256 threads x 8 float4.
// Per block: 2048 consecutive float4 = 2 (b,s)-slabs x 4 channels x 256.
// For flat float4 index i = blk*2048 + u*256 + t:
//   hw4 = t  (since u*256 is a multiple of 256)
//   bs  = blk*2 + (u>>2)
// -> each thread needs only 2 weight loads (slab 0 for u<4, slab 1 for u>=4).
//
// Two-stage reduction: no atomics (Round-1 single-address atomic tail was the
// bottleneck: 42 us with VALU 3%, HBM 17% -> serialization, not BW).

#define NBLK 1200

__global__ __launch_bounds__(256) void loss_stage1(
    const float4* __restrict__ outp,
    const float4* __restrict__ conv,
    const float4* __restrict__ wgt,
    float* __restrict__ partial)
{
    const int t = threadIdx.x;
    const int base = blockIdx.x * 2048 + t;

    // Issue all global loads up front: 18 independent 16B loads in flight.
    float4 o[8], c[8];
    #pragma unroll
    for (int u = 0; u < 8; ++u) {
        o[u] = outp[base + u * 256];
        c[u] = conv[base + u * 256];
    }
    const int wbase = blockIdx.x * 512 + t;  // (blk*2)*256 + t
    const float4 w0 = wgt[wbase];
    const float4 w1 = wgt[wbase + 256];

    float acc0 = 0.f, acc1 = 0.f;
    #pragma unroll
    for (int u = 0; u < 8; ++u) {
        const float4 w = (u < 4) ? w0 : w1;
        const float dx = c[u].x - o[u].x;
        const float dy = c[u].y - o[u].y;
        const float dz = c[u].z - o[u].z;
        const float dw = c[u].w - o[u].w;
        if (u & 1)
            acc1 += w.x * dx * dx + w.y * dy * dy + w.z * dz * dz + w.w * dw * dw;
        else
            acc0 += w.x * dx * dx + w.y * dy * dy + w.z * dz * dz + w.w * dw * dw;
    }
    float acc = acc0 + acc1;

    // 64-lane wave reduction
    #pragma unroll
    for (int off = 32; off > 0; off >>= 1)
        acc += __shfl_down(acc, off, 64);

    __shared__ float sbuf[4];
    const int lane = t & 63;
    const int wid  = t >> 6;
    if (lane == 0) sbuf[wid] = acc;
    __syncthreads();
    if (t == 0)
        partial[blockIdx.x] = (sbuf[0] + sbuf[1]) + (sbuf[2] + sbuf[3]);
}

__global__ __launch_bounds__(256) void loss_stage2(
    const float* __restrict__ partial,
    float* __restrict__ result)
{
    const int t = threadIdx.x;
    float acc = 0.f;
    for (int i = t; i < NBLK; i += 256) acc += partial[i];

    #pragma unroll
    for (int off = 32; off > 0; off >>= 1)
        acc += __shfl_down(acc, off, 64);

    __shared__ float sbuf[4];
    const int lane = t & 63;
    const int wid  = t >> 6;
    if (lane == 0) sbuf[wid] = acc;
    __syncthreads();
    if (t == 0)
        result[0] = ((sbuf[0] + sbuf[1]) + (sbuf[2] + sbuf[3])) * (1.0f / 1024.0f);
}

extern "C" void kernel_launch(void* const* d_in, const int* in_sizes, int n_in,
                              void* d_out, int out_size, void* d_ws, size_t ws_size,
                              hipStream_t stream) {
    const float4* outp = (const float4*)d_in[0];  // output   [8,300,4,32,32]
    const float4* conv = (const float4*)d_in[1];  // convdata [8,300,4,32,32]
    const float4* wgt  = (const float4*)d_in[2];  // visweight[8,300,32,32]
    float* partial = (float*)d_ws;                // 1200 floats of scratch
    float* result  = (float*)d_out;

    loss_stage1<<<NBLK, 256, 0, stream>>>(outp, conv, wgt, partial);
    loss_stage2<<<1, 256, 0, stream>>>(partial, result);
}